// Round 11
// baseline (445.670 us; speedup 1.0000x reference)
//
#include <hip/hip_runtime.h>

#define NSLOT 32
#define BN_EPS 1e-5f
#define NSB 256             // scatter blocks (1 edge-slice each)
#define BKBITS 8
#define BKN 256             // nodes per bucket (= sort block size)
#define MAXBUCK 512         // LDS bound: nbuck = cdiv(N,256) <= 512 for N <= 131072
#define AGTILE 128          // dst-nodes per aggregate tile
#define SCOLCAP 4096        // LDS col window cap (mean 2048; ~45 sigma)

#define HWREG(id, off, sz) ((id) | ((off) << 6) | (((sz) - 1) << 11))
#define HW_REG_XCC_ID 20

static inline int cdiv_h(int a, int b) { return (a + b - 1) / b; }

__device__ __forceinline__ float4 f4add(float4 a, float4 b) {
    return make_float4(a.x + b.x, a.y + b.y, a.z + b.z, a.w + b.w);
}

// bf16 round-to-nearest-even pack
__device__ __forceinline__ unsigned bf16rtn(float x) {
    unsigned u = __float_as_uint(x);
    return (u + 0x7FFFu + ((u >> 16) & 1u)) >> 16;
}
__device__ __forceinline__ unsigned bf16pack2(float lo, float hi) {
    return bf16rtn(lo) | (bf16rtn(hi) << 16);
}

// block-wide exclusive scan, 256 threads (4 waves)
__device__ __forceinline__ int blk_excl_scan256(int v, int t) {
    __shared__ int wsum[4];
    int l = t & 63, w = t >> 6;
    int incl = v;
#pragma unroll
    for (int off = 1; off < 64; off <<= 1) {
        int o = __shfl_up(incl, off, 64);
        if (l >= off) incl += o;
    }
    if (l == 63) wsum[w] = incl;
    __syncthreads();
    int wofs = 0;
#pragma unroll
    for (int i = 0; i < 4; i++) wofs += (i < w) ? wsum[i] : 0;
    __syncthreads();
    return wofs + incl - v;
}

// block-wide exclusive scan, 512 threads (8 waves)
__device__ __forceinline__ int blk_excl_scan512(int v, int t) {
    __shared__ int wsum8[8];
    int l = t & 63, w = t >> 6;
    int incl = v;
#pragma unroll
    for (int off = 1; off < 64; off <<= 1) {
        int o = __shfl_up(incl, off, 64);
        if (l >= off) incl += o;
    }
    if (l == 63) wsum8[w] = incl;
    __syncthreads();
    int wofs = 0;
#pragma unroll
    for (int i = 0; i < 8; i++) wofs += (i < w) ? wsum8[i] : 0;
    __syncthreads();
    return wofs + incl - v;
}

// per-block BN coef compute from 32-slot partials (ch in [0,32))
__device__ __forceinline__ void bn_coef(const float* __restrict__ sSum, const float* __restrict__ sSq,
                                        const float* __restrict__ bg, const float* __restrict__ bb,
                                        float invN, int ch, float* aOut, float* cOut) {
    float S = 0.f, Q = 0.f;
#pragma unroll
    for (int s = 0; s < NSLOT; s++) { S += sSum[s * 32 + ch]; Q += sSq[s * 32 + ch]; }
    float m = S * invN;
    float var = Q * invN - m * m;
    if (var < 0.f) var = 0.f;
    float iv = rsqrtf(var + BN_EPS);
    float a = bg[ch] * iv;
    *aOut = a;
    *cOut = bb[ch] - m * a;
}

// ---------------- grouping pass 1: per-block bucket histogram + stats/queue zero-init ------------

__global__ __launch_bounds__(256) void k_hist(const int* __restrict__ dst, int* __restrict__ histT,
                                              float* __restrict__ sSum, float* __restrict__ sSq,
                                              int* __restrict__ qcnt,
                                              int E, int nbuck, int chunk) {
    __shared__ int bins[MAXBUCK];
    int k = blockIdx.x, t = threadIdx.x;
    if (k == 0) {    // zero BN stat slots + aggregate tile queues (replaces memsets)
        for (int i = t; i < 4 * NSLOT * 32; i += 256) { sSum[i] = 0.f; sSq[i] = 0.f; }
        if (t < 8) qcnt[t] = 0;
    }
    for (int b = t; b < nbuck; b += 256) bins[b] = 0;
    __syncthreads();
    int lo = k * chunk, hi = lo + chunk; if (hi > E) hi = E;
    for (int i = lo + t; i < hi; i += 256) atomicAdd(&bins[dst[i] >> BKBITS], 1);
    __syncthreads();
    for (int b = t; b < nbuck; b += 256) histT[k * nbuck + b] = bins[b];
}

// ---------------- grouping pass 1b: per-bucket scan over cells (+ folded gstart) ----------------

__global__ __launch_bounds__(256) void k_scanA(const int* __restrict__ histT, int* __restrict__ prefixB,
                                               int* __restrict__ totalP, int* __restrict__ totalU,
                                               const int* __restrict__ gid, int* __restrict__ gstart,
                                               int nbuck, int N, int G) {
    int b = blockIdx.x, k = threadIdx.x;
    int i = b * 256 + k;
    if (i < N) {
        int g = gid[i];
        int gp = (i == 0) ? -1 : gid[i - 1];
        for (int x = gp + 1; x <= g; ++x) gstart[x] = i;
        if (i == N - 1) { for (int x = g + 1; x <= G; ++x) gstart[x] = N; }
    }
    int c = histT[k * nbuck + b];
    int pad = (c + 15) & ~15;
    int ep = blk_excl_scan256(pad, k);
    prefixB[b * NSB + k] = ep;
    int ec = blk_excl_scan256(c, k);
    if (k == NSB - 1) { totalP[b] = ep + pad; totalU[b] = ec + c; }
}

__global__ __launch_bounds__(512) void k_scanB(const int* __restrict__ totalP, const int* __restrict__ totalU,
                                               int* __restrict__ baseP, int* __restrict__ baseU, int nbuck) {
    int t = threadIdx.x;
    int vp = (t < nbuck) ? totalP[t] : 0;
    int vu = (t < nbuck) ? totalU[t] : 0;
    int ep = blk_excl_scan512(vp, t);
    int eu = blk_excl_scan512(vu, t);
    if (t < nbuck) { baseP[t] = ep; baseU[t] = eu; }
}

// ---------------- grouping pass 2: deterministic scatter (LDS cursors, no global atomics) --------
// packed entry: (dst&255)<<24 | src   (requires N < 2^24)

__global__ __launch_bounds__(256) void k_scatter2(const int* __restrict__ src, const int* __restrict__ dst,
                                                  const int* __restrict__ baseP, const int* __restrict__ prefixB,
                                                  unsigned* __restrict__ ebuf, int E, int nbuck, int chunk) {
    __shared__ int cur[MAXBUCK];
    int k = blockIdx.x, t = threadIdx.x;
    for (int b = t; b < nbuck; b += 256) cur[b] = baseP[b] + prefixB[b * NSB + k];
    __syncthreads();
    int lo = k * chunk, hi = lo + chunk; if (hi > E) hi = E;
    for (int i = lo + t; i < hi; i += 256) {
        int d = dst[i], s = src[i];
        int b = d >> BKBITS;
        int pos = atomicAdd(&cur[b], 1);
        ebuf[pos] = ((unsigned)(d & (BKN - 1)) << 24) | (unsigned)s;
    }
}

// ---------------- grouping pass 3: per-bucket counting sort -> node-grouped compact col + rs/re --

__global__ __launch_bounds__(256) void k_sortb(const unsigned* __restrict__ ebuf, const int* __restrict__ histT,
                                               const int* __restrict__ baseP, const int* __restrict__ prefixB,
                                               const int* __restrict__ baseU,
                                               int* __restrict__ col, int* __restrict__ rs, int* __restrict__ re,
                                               int nbuck, int N) {
    __shared__ int binCnt[BKN], binStart[BKN], cursor[BKN];
    __shared__ int cellBase[NSB], cellCnt[NSB];
    int b = blockIdx.x, t = threadIdx.x;
    cellBase[t] = baseP[b] + prefixB[b * NSB + t];
    cellCnt[t]  = histT[t * nbuck + b];
    binCnt[t] = 0; cursor[t] = 0;
    __syncthreads();
    {
        int cb = cellBase[t], cc = cellCnt[t];
        for (int j = 0; j < cc; j++) atomicAdd(&binCnt[ebuf[cb + j] >> 24], 1);
    }
    __syncthreads();
    int bs = blk_excl_scan256(binCnt[t], t);
    binStart[t] = bs;
    __syncthreads();
    int colBase = baseU[b];
    {
        int cb = cellBase[t], cc = cellCnt[t];
        for (int j = 0; j < cc; j++) {
            unsigned e = ebuf[cb + j];
            int l = e >> 24;
            int pos = binStart[l] + atomicAdd(&cursor[l], 1);
            col[colBase + pos] = (int)(e & 0xFFFFFFu);
        }
    }
    int node = b * BKN + t;
    if (node < N) {
        rs[node] = colBase + binStart[t];
        re[node] = colBase + binStart[t] + binCnt[t];
    }
}

// ---------------- per-node transform -> bf16 p, CHANNEL-SPLIT (pLo: ch0-15, pHi: ch16-31) -------
// Each half is 32 B/node (3.2 MB total) -> fits one XCD's 4 MB L2 for the aggregate gather.
// AFF=1: input y is split halves; also folds previous layer's BN finalize.

template <int AFF>
__global__ __launch_bounds__(256) void k_transform(const float* __restrict__ xinLo, const float* __restrict__ xinHi,
                                                   const float* __restrict__ W,
                                                   const float* __restrict__ sSum, const float* __restrict__ sSq,
                                                   const float* __restrict__ bg, const float* __restrict__ bb,
                                                   uint4* __restrict__ pLo, uint4* __restrict__ pHi,
                                                   int n, float invN) {
    __shared__ float sW[32][32];
    __shared__ float sA[32], sC[32];
    int t = threadIdx.x;
    for (int i = t; i < 1024; i += 256) sW[i >> 5][i & 31] = W[i];
    if (AFF && t < 32) bn_coef(sSum, sSq, bg, bb, invN, t, &sA[t], &sC[t]);
    __syncthreads();
    int node = blockIdx.x * 256 + t;
    if (node >= n) return;
    float x[32];
    if (AFF) {
        const float4* l4 = (const float4*)(xinLo + (size_t)node * 16);
        const float4* h4 = (const float4*)(xinHi + (size_t)node * 16);
#pragma unroll
        for (int q = 0; q < 4; q++) {
            float4 v = l4[q];
            x[4*q] = v.x; x[4*q+1] = v.y; x[4*q+2] = v.z; x[4*q+3] = v.w;
            float4 w = h4[q];
            x[16+4*q] = w.x; x[16+4*q+1] = w.y; x[16+4*q+2] = w.z; x[16+4*q+3] = w.w;
        }
#pragma unroll
        for (int k = 0; k < 32; k++) {
            float v = sA[k] * x[k] + sC[k];
            x[k] = v > 0.f ? v : 0.f;
        }
    } else {
        const float4* s4 = (const float4*)(xinLo + (size_t)node * 32);
#pragma unroll
        for (int q = 0; q < 8; q++) {
            float4 v = s4[q];
            x[4*q] = v.x; x[4*q+1] = v.y; x[4*q+2] = v.z; x[4*q+3] = v.w;
        }
    }
    float acc[32];
#pragma unroll
    for (int f = 0; f < 32; f++) acc[f] = 0.f;
#pragma unroll
    for (int k = 0; k < 32; k++) {
        float xv = x[k];
#pragma unroll
        for (int f = 0; f < 32; f++) acc[f] += xv * sW[k][f];
    }
#pragma unroll
    for (int half = 0; half < 2; half++) {
        uint4* d = (half ? pHi : pLo) + (size_t)node * 2;
        const float* a = acc + half * 16;
#pragma unroll
        for (int q = 0; q < 2; q++) {
            uint4 o;
            o.x = bf16pack2(a[8*q+0], a[8*q+1]);
            o.y = bf16pack2(a[8*q+2], a[8*q+3]);
            o.z = bf16pack2(a[8*q+4], a[8*q+5]);
            o.w = bf16pack2(a[8*q+6], a[8*q+7]);
            d[q] = o;
        }
    }
}

// layer 3: p3[v] = relu(a*y2+c) . w3   (split y2 input; folds its BN coefs)
__global__ __launch_bounds__(256) void k_transform3(const float* __restrict__ yLo, const float* __restrict__ yHi,
                                                    const float* __restrict__ w3,
                                                    const float* __restrict__ sSum, const float* __restrict__ sSq,
                                                    const float* __restrict__ bg, const float* __restrict__ bb,
                                                    float* __restrict__ p3, int n, float invN) {
    __shared__ float sw[32], sA[32], sC[32];
    int t = threadIdx.x;
    if (t < 32) { sw[t] = w3[t]; bn_coef(sSum, sSq, bg, bb, invN, t, &sA[t], &sC[t]); }
    __syncthreads();
    int i = blockIdx.x * 256 + t;
    if (i >= n) return;
    float acc = 0.f;
#pragma unroll
    for (int half = 0; half < 2; half++) {
        const float4* x4 = (const float4*)(((half) ? yHi : yLo) + (size_t)i * 16);
#pragma unroll
        for (int q = 0; q < 4; q++) {
            float4 v = x4[q];
            float vv[4] = {v.x, v.y, v.z, v.w};
#pragma unroll
            for (int r = 0; r < 4; r++) {
                int k = half * 16 + q * 4 + r;
                float xv = sA[k] * vv[r] + sC[k];
                xv = xv > 0.f ? xv : 0.f;
                acc += xv * sw[k];
            }
        }
    }
    p3[i] = acc;
}

// ---------------- aggregation, channel-split tile-queue kernel ----------------
// A block reads its physical XCC_ID, prefers queue half = xcc&1, drains 128-node tiles for that
// 16-channel half (2 lanes x 16B/node): ~4 XCDs gather repeatedly from the SAME 3.2 MB half-array
// -> L2-resident. Steal phase drains the other queue (correct under any XCD mapping, G16).

__global__ __launch_bounds__(256) void k_agg(const uint4* __restrict__ pLo, const uint4* __restrict__ pHi,
                                             const int* __restrict__ rs, const int* __restrict__ re,
                                             const int* __restrict__ col, const float* __restrict__ bias,
                                             float4* __restrict__ yLo, float4* __restrict__ yHi,
                                             float* __restrict__ sSum, float* __restrict__ sSq,
                                             int* __restrict__ qcnt, int n, int numTiles) {
    __shared__ int scol[SCOLCAP];
    __shared__ int stile;
    __shared__ float sS[AGTILE][16], sQ[AGTILE][16];
    __shared__ float pS[8][16], pQ[8][16];
    int t = threadIdx.x;
    int lane = t & 1;          // 16B chunk: channels half*16 + lane*8 .. +7
    int grp = t >> 1;          // 0..127 : node within tile
    int pref = __builtin_amdgcn_s_getreg(HWREG(HW_REG_XCC_ID, 0, 4)) & 1;
#pragma unroll
    for (int phase = 0; phase < 2; phase++) {
        int half = pref ^ phase;
        const uint4* pb = half ? pHi : pLo;
        float4* y4 = half ? yHi : yLo;
        for (;;) {
            __syncthreads();                      // protect stile/scol reuse
            if (t == 0) stile = atomicAdd(&qcnt[half], 1);
            __syncthreads();
            int tile = stile;
            if (tile >= numTiles) break;
            int node0 = tile * AGTILE;
            int node = node0 + grp;
            int last = node0 + AGTILE - 1; if (last > n - 1) last = n - 1;
            int base0 = rs[node0];
            int len = re[last] - base0;
            bool lds = (len <= SCOLCAP);
            if (lds) { for (int i = t; i < len; i += 256) scol[i] = col[base0 + i]; }
            __syncthreads();
            float accA[8], accB[8];
#pragma unroll
            for (int q = 0; q < 8; q++) { accA[q] = 0.f; accB[q] = 0.f; }
            float vout[8];
#pragma unroll
            for (int q = 0; q < 8; q++) vout[q] = 0.f;
            if (node < n) {
                int s0 = rs[node], s1 = re[node];
#define GATH(vv, c) uint4 vv = pb[(size_t)(c) * 2 + lane]
#define ACC(dst, vv) \
                dst[0] += __uint_as_float((vv).x << 16); dst[1] += __uint_as_float((vv).x & 0xFFFF0000u); \
                dst[2] += __uint_as_float((vv).y << 16); dst[3] += __uint_as_float((vv).y & 0xFFFF0000u); \
                dst[4] += __uint_as_float((vv).z << 16); dst[5] += __uint_as_float((vv).z & 0xFFFF0000u); \
                dst[6] += __uint_as_float((vv).w << 16); dst[7] += __uint_as_float((vv).w & 0xFFFF0000u)
                if (lds) {
                    int j = s0 - base0, j1 = s1 - base0;
                    for (; j + 8 <= j1; j += 8) {
                        int c0 = scol[j], c1 = scol[j + 1], c2 = scol[j + 2], c3 = scol[j + 3];
                        int c4 = scol[j + 4], c5 = scol[j + 5], c6 = scol[j + 6], c7 = scol[j + 7];
                        GATH(g0, c0); GATH(g1, c1); GATH(g2, c2); GATH(g3, c3);
                        GATH(g4, c4); GATH(g5, c5); GATH(g6, c6); GATH(g7, c7);
                        ACC(accA, g0); ACC(accB, g1); ACC(accA, g2); ACC(accB, g3);
                        ACC(accA, g4); ACC(accB, g5); ACC(accA, g6); ACC(accB, g7);
                    }
                    for (; j < j1; ++j) { GATH(g, scol[j]); ACC(accA, g); }
                } else {
                    for (int j = s0; j < s1; ++j) { GATH(g, col[j]); ACC(accA, g); }
                }
#undef GATH
#undef ACC
                int deg = s1 - s0;
                float inv = (deg > 0) ? 1.f / (float)deg : 1.f;
                const float4* b4 = (const float4*)bias;
                float4 b0 = b4[half * 4 + lane * 2], b1 = b4[half * 4 + lane * 2 + 1];
                vout[0] = (accA[0] + accB[0]) * inv + b0.x;
                vout[1] = (accA[1] + accB[1]) * inv + b0.y;
                vout[2] = (accA[2] + accB[2]) * inv + b0.z;
                vout[3] = (accA[3] + accB[3]) * inv + b0.w;
                vout[4] = (accA[4] + accB[4]) * inv + b1.x;
                vout[5] = (accA[5] + accB[5]) * inv + b1.y;
                vout[6] = (accA[6] + accB[6]) * inv + b1.z;
                vout[7] = (accA[7] + accB[7]) * inv + b1.w;
                y4[(size_t)node * 4 + lane * 2]     = make_float4(vout[0], vout[1], vout[2], vout[3]);
                y4[(size_t)node * 4 + lane * 2 + 1] = make_float4(vout[4], vout[5], vout[6], vout[7]);
            }
            // BN stats for this half's 16 channels
            ((float4*)&sS[grp][lane * 8])[0] = make_float4(vout[0], vout[1], vout[2], vout[3]);
            ((float4*)&sS[grp][lane * 8])[1] = make_float4(vout[4], vout[5], vout[6], vout[7]);
            ((float4*)&sQ[grp][lane * 8])[0] = make_float4(vout[0]*vout[0], vout[1]*vout[1], vout[2]*vout[2], vout[3]*vout[3]);
            ((float4*)&sQ[grp][lane * 8])[1] = make_float4(vout[4]*vout[4], vout[5]*vout[5], vout[6]*vout[6], vout[7]*vout[7]);
            __syncthreads();
            if (t < 128) {
                int ch = t & 15, seg = t >> 4;
                float s = 0.f, qq = 0.f;
#pragma unroll
                for (int r = 0; r < 16; r++) { s += sS[seg * 16 + r][ch]; qq += sQ[seg * 16 + r][ch]; }
                pS[seg][ch] = s; pQ[seg][ch] = qq;
            }
            __syncthreads();
            if (t < 16) {
                float s = 0.f, qq = 0.f;
#pragma unroll
                for (int i = 0; i < 8; i++) { s += pS[i][t]; qq += pQ[i][t]; }
                int slot = tile & (NSLOT - 1);
                atomicAdd(&sSum[slot * 32 + half * 16 + t], s);
                atomicAdd(&sSq[slot * 32 + half * 16 + t], qq);
            }
        }
    }
}

__global__ __launch_bounds__(256) void k_aggregate3(const float* __restrict__ p3, const int* __restrict__ rs,
                                                    const int* __restrict__ re, const int* __restrict__ col,
                                                    const float* __restrict__ b1,
                                                    float* __restrict__ y3, float* __restrict__ sSum,
                                                    float* __restrict__ sSq, int n) {
    int i = blockIdx.x * 256 + threadIdx.x;
    float lsum = 0.f, lsq = 0.f;
    if (i < n) {
        int s0 = rs[i], s1 = re[i];
        float a0 = 0.f, a1 = 0.f, a2 = 0.f, a3 = 0.f;
        int j = s0;
        for (; j + 4 <= s1; j += 4) {
            int c0 = col[j], c1 = col[j + 1], c2 = col[j + 2], c3 = col[j + 3];
            a0 += p3[c0]; a1 += p3[c1]; a2 += p3[c2]; a3 += p3[c3];
        }
        for (; j < s1; ++j) a0 += p3[col[j]];
        float acc = (a0 + a1) + (a2 + a3);
        float inv = (s1 > s0) ? 1.f / (float)(s1 - s0) : 1.f;
        float v = acc * inv + b1[0];
        y3[i] = v; lsum = v; lsq = v * v;
    }
    __shared__ float sS[256], sQ[256];
    int t = threadIdx.x;
    sS[t] = lsum; sQ[t] = lsq;
    __syncthreads();
    for (int s = 128; s > 0; s >>= 1) {
        if (t < s) { sS[t] += sS[t + s]; sQ[t] += sQ[t + s]; }
        __syncthreads();
    }
    if (t == 0) {
        int slot = blockIdx.x & (NSLOT - 1);
        atomicAdd(&sSum[slot * 32], sS[0]);
        atomicAdd(&sSq[slot * 32], sQ[0]);
    }
}

// ---------------- per-graph mean pool + MLP (folds all 97 BN coefs; split y inputs) -------------

__global__ __launch_bounds__(256) void k_pool_mlp(const float* __restrict__ h,
                                                  const float* __restrict__ y0L, const float* __restrict__ y0H,
                                                  const float* __restrict__ y1L, const float* __restrict__ y1H,
                                                  const float* __restrict__ y2L, const float* __restrict__ y2H,
                                                  const float* __restrict__ y3,
                                                  const float* __restrict__ sSum, const float* __restrict__ sSq,
                                                  const float* __restrict__ bg0, const float* __restrict__ bb0,
                                                  const float* __restrict__ bg1, const float* __restrict__ bb1,
                                                  const float* __restrict__ bg2, const float* __restrict__ bb2,
                                                  const float* __restrict__ bg3, const float* __restrict__ bb3,
                                                  const int* __restrict__ gstart,
                                                  const float* __restrict__ w0, const float* __restrict__ b0,
                                                  const float* __restrict__ w1, const float* __restrict__ b1,
                                                  const float* __restrict__ w2, const float* __restrict__ b2,
                                                  float* __restrict__ out, float invN) {
    __shared__ float pcA[128], pcC[128];
    int g = blockIdx.x;
    int t = threadIdx.x;
    if (t < 97) {
        int layer = (t == 96) ? 3 : (t >> 5);
        int ch = t & 31;
        const float* bg = (layer == 0) ? bg0 : (layer == 1) ? bg1 : (layer == 2) ? bg2 : bg3;
        const float* bb = (layer == 0) ? bb0 : (layer == 1) ? bb1 : (layer == 2) ? bb2 : bb3;
        bn_coef(sSum + layer * NSLOT * 32, sSq + layer * NSLOT * 32, bg, bb, invN, ch, &pcA[t], &pcC[t]);
    }
    __syncthreads();
    int s0 = gstart[g], s1 = gstart[g + 1];
    int lane = t & 31, slot = t >> 5;
    int arr = lane >> 3, sub = lane & 7;
    const float4* bp;
    int stride, offs;
    if (arr == 0) { bp = (const float4*)h; stride = 8; offs = sub; }
    else {
        const float* lo = (arr == 1) ? y0L : (arr == 2) ? y1L : y2L;
        const float* hi = (arr == 1) ? y0H : (arr == 2) ? y1H : y2H;
        bp = (const float4*)((sub < 4) ? lo : hi);
        stride = 4; offs = sub & 3;
    }
    float4 a4 = make_float4(1.f, 1.f, 1.f, 1.f);
    float4 c4 = make_float4(0.f, 0.f, 0.f, 0.f);
    bool aff = (arr > 0);
    if (aff) {
        a4 = ((const float4*)pcA)[(arr - 1) * 8 + sub];
        c4 = ((const float4*)pcC)[(arr - 1) * 8 + sub];
    }
    float4 acc = make_float4(0.f, 0.f, 0.f, 0.f);
    for (int n = s0 + slot; n < s1; n += 8) {
        float4 v = bp[(size_t)n * stride + offs];
        if (aff) {
            float vx = fmaf(a4.x, v.x, c4.x); vx = vx > 0.f ? vx : 0.f;
            float vy = fmaf(a4.y, v.y, c4.y); vy = vy > 0.f ? vy : 0.f;
            float vz = fmaf(a4.z, v.z, c4.z); vz = vz > 0.f ? vz : 0.f;
            float vw = fmaf(a4.w, v.w, c4.w); vw = vw > 0.f ? vw : 0.f;
            v = make_float4(vx, vy, vz, vw);
        }
        acc = f4add(acc, v);
    }
    __shared__ float sP[8][128];
    __shared__ float sY[8];
    ((float4*)&sP[slot][lane * 4])[0] = acc;
    if (t < 8) {
        float a = pcA[96], c = pcC[96], s = 0.f;
        for (int n = s0 + t; n < s1; n += 8) {
            float v = fmaf(a, y3[n], c);
            s += v > 0.f ? v : 0.f;
        }
        sY[t] = s;
    }
    __syncthreads();
    __shared__ float hg[129];
    __shared__ float hid1[128];
    __shared__ float hid2[64];
    float inv = (s1 > s0) ? 1.f / (float)(s1 - s0) : 1.f;
    if (t < 128) {
        float S = 0.f;
#pragma unroll
        for (int s = 0; s < 8; s++) S += sP[s][t];
        hg[t] = S * inv;
    } else if (t == 128) {
        float S = 0.f;
#pragma unroll
        for (int s = 0; s < 8; s++) S += sY[s];
        hg[128] = S * inv;
    }
    __syncthreads();
    if (t < 128) {
        float a = b0[t];
        for (int i = 0; i < 129; i++) a += hg[i] * w0[i * 128 + t];
        hid1[t] = a > 0.f ? a : 0.f;
    }
    __syncthreads();
    if (t < 64) {
        float a = b1[t];
        for (int i = 0; i < 128; i++) a += hid1[i] * w1[i * 64 + t];
        hid2[t] = a > 0.f ? a : 0.f;
    }
    __syncthreads();
    if (t < 64) {
        float v = hid2[t] * w2[t];
        for (int off = 32; off > 0; off >>= 1) v += __shfl_down(v, off, 64);
        if (t == 0) out[g] = v + b2[0];
    }
}

// ---------------- launcher ----------------

extern "C" void kernel_launch(void* const* d_in, const int* in_sizes, int n_in,
                              void* d_out, int out_size, void* d_ws, size_t ws_size,
                              hipStream_t stream) {
    const float* h   = (const float*)d_in[0];
    const int* src   = (const int*)d_in[1];
    const int* dst   = (const int*)d_in[2];
    const int* gid   = (const int*)d_in[3];
    const float* convw[4], *convb[4], *bng[4], *bnb[4];
    for (int i = 0; i < 4; i++) {
        convw[i] = (const float*)d_in[4 + 4 * i];
        convb[i] = (const float*)d_in[5 + 4 * i];
        bng[i]   = (const float*)d_in[6 + 4 * i];
        bnb[i]   = (const float*)d_in[7 + 4 * i];
    }
    const float* mw0 = (const float*)d_in[20];
    const float* mb0 = (const float*)d_in[21];
    const float* mw1 = (const float*)d_in[22];
    const float* mb1 = (const float*)d_in[23];
    const float* mw2 = (const float*)d_in[24];
    const float* mb2 = (const float*)d_in[25];

    const int N = in_sizes[0] / 32;
    const int E = in_sizes[1];
    const int G = out_size;
    const int nbuck = cdiv_h(N, BKN);          // <= MAXBUCK for N <= 131072
    const int chunk = cdiv_h(E, NSB);
    const int numTiles = cdiv_h(N, AGTILE);

    // workspace bump allocator (512B aligned)
    char* ws = (char*)d_ws;
    size_t off = 0;
    auto alloc = [&](size_t bytes) -> void* {
        void* p = ws + off;
        off += (bytes + 511) & ~(size_t)511;
        return p;
    };
    int* histT   = (int*)alloc((size_t)NSB * nbuck * 4);
    int* prefixB = (int*)alloc((size_t)nbuck * NSB * 4);
    int* totalP  = (int*)alloc((size_t)nbuck * 4);
    int* totalU  = (int*)alloc((size_t)nbuck * 4);
    int* basePp  = (int*)alloc((size_t)nbuck * 4);
    int* baseUp  = (int*)alloc((size_t)nbuck * 4);
    int* qcnt    = (int*)alloc((size_t)8 * 4);
    size_t ebufE = (size_t)E + (size_t)16 * NSB * nbuck;      // padded capacity (ints)
    size_t ovl   = ebufE * 4;
    size_t pB    = (size_t)N * 64;                            // pLo+pHi bf16: 64 B/node total
    if (pB > ovl) ovl = pB;
    unsigned* ebuf = (unsigned*)alloc(ovl);                    // overlay: ebuf dead after k_sortb
    uint4* pLo   = (uint4*)ebuf;
    uint4* pHi   = pLo + (size_t)N * 2;
    int* col     = (int*)alloc((size_t)E * 4);
    int* rs      = (int*)alloc((size_t)N * 4);
    int* re      = (int*)alloc((size_t)N * 4);
    int* gstart  = (int*)alloc((size_t)(G + 1) * 4);
    float* y0L   = (float*)alloc((size_t)N * 16 * 4);
    float* y0H   = (float*)alloc((size_t)N * 16 * 4);
    float* y1L   = (float*)alloc((size_t)N * 16 * 4);
    float* y1H   = (float*)alloc((size_t)N * 16 * 4);
    float* y2L   = (float*)alloc((size_t)N * 16 * 4);
    float* y2H   = (float*)alloc((size_t)N * 16 * 4);
    float* y3    = (float*)alloc((size_t)N * 4);
    float* sSum  = (float*)alloc((size_t)4 * NSLOT * 32 * 4);
    float* sSq   = (float*)alloc((size_t)4 * NSLOT * 32 * 4);
    (void)ws_size; (void)n_in;

    const int NB_N = cdiv_h(N, 256);
    const int NB_AG = 2 * numTiles;
    const float invN = 1.f / (float)N;

    // edge grouping: two-pass deterministic scatter (zero global atomics) + per-bucket sort
    k_hist<<<NSB, 256, 0, stream>>>(dst, histT, sSum, sSq, qcnt, E, nbuck, chunk);
    k_scanA<<<nbuck, 256, 0, stream>>>(histT, prefixB, totalP, totalU, gid, gstart, nbuck, N, G);
    k_scanB<<<1, 512, 0, stream>>>(totalP, totalU, basePp, baseUp, nbuck);
    k_scatter2<<<NSB, 256, 0, stream>>>(src, dst, basePp, prefixB, ebuf, E, nbuck, chunk);
    k_sortb<<<nbuck, 256, 0, stream>>>(ebuf, histT, basePp, prefixB, baseUp, col, rs, re, nbuck, N);

    // layer 0
    k_transform<0><<<NB_N, 256, 0, stream>>>(h, nullptr, convw[0], nullptr, nullptr, nullptr, nullptr,
                                             pLo, pHi, N, invN);
    k_agg<<<NB_AG, 256, 0, stream>>>(pLo, pHi, rs, re, col, convb[0], (float4*)y0L, (float4*)y0H,
                                     sSum + 0 * NSLOT * 32, sSq + 0 * NSLOT * 32, qcnt + 0, N, numTiles);
    // layer 1 (folds layer-0 BN finalize)
    k_transform<1><<<NB_N, 256, 0, stream>>>(y0L, y0H, convw[1], sSum + 0 * NSLOT * 32, sSq + 0 * NSLOT * 32,
                                             bng[0], bnb[0], pLo, pHi, N, invN);
    k_agg<<<NB_AG, 256, 0, stream>>>(pLo, pHi, rs, re, col, convb[1], (float4*)y1L, (float4*)y1H,
                                     sSum + 1 * NSLOT * 32, sSq + 1 * NSLOT * 32, qcnt + 2, N, numTiles);
    // layer 2 (folds layer-1 BN finalize)
    k_transform<1><<<NB_N, 256, 0, stream>>>(y1L, y1H, convw[2], sSum + 1 * NSLOT * 32, sSq + 1 * NSLOT * 32,
                                             bng[1], bnb[1], pLo, pHi, N, invN);
    k_agg<<<NB_AG, 256, 0, stream>>>(pLo, pHi, rs, re, col, convb[2], (float4*)y2L, (float4*)y2H,
                                     sSum + 2 * NSLOT * 32, sSq + 2 * NSLOT * 32, qcnt + 4, N, numTiles);
    // layer 3 (32 -> 1, pre-multiplied; folds layer-2 BN finalize)
    k_transform3<<<NB_N, 256, 0, stream>>>(y2L, y2H, convw[3], sSum + 2 * NSLOT * 32, sSq + 2 * NSLOT * 32,
                                           bng[2], bnb[2], (float*)pLo, N, invN);
    k_aggregate3<<<NB_N, 256, 0, stream>>>((float*)pLo, rs, re, col, convb[3], y3,
                                           sSum + 3 * NSLOT * 32, sSq + 3 * NSLOT * 32, N);

    // pooling + MLP (folds all BN coefs)
    k_pool_mlp<<<G, 256, 0, stream>>>(h, y0L, y0H, y1L, y1H, y2L, y2H, y3, sSum, sSq,
                                      bng[0], bnb[0], bng[1], bnb[1], bng[2], bnb[2], bng[3], bnb[3],
                                      gstart, mw0, mb0, mw1, mb1, mw2, mb2, (float*)d_out, invN);
}

// Round 12
// 314.576 us; speedup vs baseline: 1.4167x; 1.4167x over previous
//
#include <hip/hip_runtime.h>

#define NSLOT 32
#define BN_EPS 1e-5f
#define NSB 256             // scatter blocks (1 edge-slice each)
#define BKBITS 8
#define BKN 256             // nodes per bucket (= sort block size)
#define MAXBUCK 512         // LDS bound: nbuck = cdiv(N,256) <= 512 for N <= 131072

static inline int cdiv_h(int a, int b) { return (a + b - 1) / b; }

__device__ __forceinline__ float4 f4add(float4 a, float4 b) {
    return make_float4(a.x + b.x, a.y + b.y, a.z + b.z, a.w + b.w);
}

// bf16 round-to-nearest-even pack / unpack
__device__ __forceinline__ unsigned bf16rtn(float x) {
    unsigned u = __float_as_uint(x);
    return (u + 0x7FFFu + ((u >> 16) & 1u)) >> 16;
}
__device__ __forceinline__ unsigned bf16pack2(float lo, float hi) {
    return bf16rtn(lo) | (bf16rtn(hi) << 16);
}
__device__ __forceinline__ float bfLO(unsigned u) { return __uint_as_float(u << 16); }
__device__ __forceinline__ float bfHI(unsigned u) { return __uint_as_float(u & 0xFFFF0000u); }

// block-wide exclusive scan, 256 threads (4 waves)
__device__ __forceinline__ int blk_excl_scan256(int v, int t) {
    __shared__ int wsum[4];
    int l = t & 63, w = t >> 6;
    int incl = v;
#pragma unroll
    for (int off = 1; off < 64; off <<= 1) {
        int o = __shfl_up(incl, off, 64);
        if (l >= off) incl += o;
    }
    if (l == 63) wsum[w] = incl;
    __syncthreads();
    int wofs = 0;
#pragma unroll
    for (int i = 0; i < 4; i++) wofs += (i < w) ? wsum[i] : 0;
    __syncthreads();
    return wofs + incl - v;
}

// block-wide exclusive scan, 512 threads (8 waves)
__device__ __forceinline__ int blk_excl_scan512(int v, int t) {
    __shared__ int wsum8[8];
    int l = t & 63, w = t >> 6;
    int incl = v;
#pragma unroll
    for (int off = 1; off < 64; off <<= 1) {
        int o = __shfl_up(incl, off, 64);
        if (l >= off) incl += o;
    }
    if (l == 63) wsum8[w] = incl;
    __syncthreads();
    int wofs = 0;
#pragma unroll
    for (int i = 0; i < 8; i++) wofs += (i < w) ? wsum8[i] : 0;
    __syncthreads();
    return wofs + incl - v;
}

// per-block BN coef compute from 32-slot partials (ch in [0,32))
__device__ __forceinline__ void bn_coef(const float* __restrict__ sSum, const float* __restrict__ sSq,
                                        const float* __restrict__ bg, const float* __restrict__ bb,
                                        float invN, int ch, float* aOut, float* cOut) {
    float S = 0.f, Q = 0.f;
#pragma unroll
    for (int s = 0; s < NSLOT; s++) { S += sSum[s * 32 + ch]; Q += sSq[s * 32 + ch]; }
    float m = S * invN;
    float var = Q * invN - m * m;
    if (var < 0.f) var = 0.f;
    float iv = rsqrtf(var + BN_EPS);
    float a = bg[ch] * iv;
    *aOut = a;
    *cOut = bb[ch] - m * a;
}

// ---------------- grouping pass 1: per-block bucket histogram + stats zero-init ----------------

__global__ __launch_bounds__(256) void k_hist(const int* __restrict__ dst, int* __restrict__ histT,
                                              float* __restrict__ sSum, float* __restrict__ sSq,
                                              int E, int nbuck, int chunk) {
    __shared__ int bins[MAXBUCK];
    int k = blockIdx.x, t = threadIdx.x;
    if (k == 0) {    // zero BN stat slots (replaces memsets)
        for (int i = t; i < 4 * NSLOT * 32; i += 256) { sSum[i] = 0.f; sSq[i] = 0.f; }
    }
    for (int b = t; b < nbuck; b += 256) bins[b] = 0;
    __syncthreads();
    int lo = k * chunk, hi = lo + chunk; if (hi > E) hi = E;
    for (int i = lo + t; i < hi; i += 256) atomicAdd(&bins[dst[i] >> BKBITS], 1);
    __syncthreads();
    for (int b = t; b < nbuck; b += 256) histT[k * nbuck + b] = bins[b];
}

// ---------------- grouping pass 1b: per-bucket scan over cells (+ folded gstart) ----------------

__global__ __launch_bounds__(256) void k_scanA(const int* __restrict__ histT, int* __restrict__ prefixB,
                                               int* __restrict__ totalP, int* __restrict__ totalU,
                                               const int* __restrict__ gid, int* __restrict__ gstart,
                                               int nbuck, int N, int G) {
    int b = blockIdx.x, k = threadIdx.x;
    int i = b * 256 + k;
    if (i < N) {
        int g = gid[i];
        int gp = (i == 0) ? -1 : gid[i - 1];
        for (int x = gp + 1; x <= g; ++x) gstart[x] = i;
        if (i == N - 1) { for (int x = g + 1; x <= G; ++x) gstart[x] = N; }
    }
    int c = histT[k * nbuck + b];
    int pad = (c + 15) & ~15;
    int ep = blk_excl_scan256(pad, k);
    prefixB[b * NSB + k] = ep;
    int ec = blk_excl_scan256(c, k);
    if (k == NSB - 1) { totalP[b] = ep + pad; totalU[b] = ec + c; }
}

__global__ __launch_bounds__(512) void k_scanB(const int* __restrict__ totalP, const int* __restrict__ totalU,
                                               int* __restrict__ baseP, int* __restrict__ baseU, int nbuck) {
    int t = threadIdx.x;
    int vp = (t < nbuck) ? totalP[t] : 0;
    int vu = (t < nbuck) ? totalU[t] : 0;
    int ep = blk_excl_scan512(vp, t);
    int eu = blk_excl_scan512(vu, t);
    if (t < nbuck) { baseP[t] = ep; baseU[t] = eu; }
}

// ---------------- grouping pass 2: deterministic scatter (LDS cursors, no global atomics) --------
// packed entry: (dst&255)<<24 | src   (requires N < 2^24)

__global__ __launch_bounds__(256) void k_scatter2(const int* __restrict__ src, const int* __restrict__ dst,
                                                  const int* __restrict__ baseP, const int* __restrict__ prefixB,
                                                  unsigned* __restrict__ ebuf, int E, int nbuck, int chunk) {
    __shared__ int cur[MAXBUCK];
    int k = blockIdx.x, t = threadIdx.x;
    for (int b = t; b < nbuck; b += 256) cur[b] = baseP[b] + prefixB[b * NSB + k];
    __syncthreads();
    int lo = k * chunk, hi = lo + chunk; if (hi > E) hi = E;
    for (int i = lo + t; i < hi; i += 256) {
        int d = dst[i], s = src[i];
        int b = d >> BKBITS;
        int pos = atomicAdd(&cur[b], 1);
        ebuf[pos] = ((unsigned)(d & (BKN - 1)) << 24) | (unsigned)s;
    }
}

// ---------------- grouping pass 3: per-bucket counting sort -> node-grouped compact col + rs/re --

__global__ __launch_bounds__(256) void k_sortb(const unsigned* __restrict__ ebuf, const int* __restrict__ histT,
                                               const int* __restrict__ baseP, const int* __restrict__ prefixB,
                                               const int* __restrict__ baseU,
                                               int* __restrict__ col, int* __restrict__ rs, int* __restrict__ re,
                                               int nbuck, int N) {
    __shared__ int binCnt[BKN], binStart[BKN], cursor[BKN];
    __shared__ int cellBase[NSB], cellCnt[NSB];
    int b = blockIdx.x, t = threadIdx.x;
    cellBase[t] = baseP[b] + prefixB[b * NSB + t];
    cellCnt[t]  = histT[t * nbuck + b];
    binCnt[t] = 0; cursor[t] = 0;
    __syncthreads();
    {
        int cb = cellBase[t], cc = cellCnt[t];
        for (int j = 0; j < cc; j++) atomicAdd(&binCnt[ebuf[cb + j] >> 24], 1);
    }
    __syncthreads();
    int bs = blk_excl_scan256(binCnt[t], t);
    binStart[t] = bs;
    __syncthreads();
    int colBase = baseU[b];
    {
        int cb = cellBase[t], cc = cellCnt[t];
        for (int j = 0; j < cc; j++) {
            unsigned e = ebuf[cb + j];
            int l = e >> 24;
            int pos = binStart[l] + atomicAdd(&cursor[l], 1);
            col[colBase + pos] = (int)(e & 0xFFFFFFu);
        }
    }
    int node = b * BKN + t;
    if (node < N) {
        rs[node] = colBase + binStart[t];
        re[node] = colBase + binStart[t] + binCnt[t];
    }
}

// ---------------- per-node transform: p = (relu(a*y+c)) @ W -> bf16 (or h @ W for layer 0) --------
// AFF=1: input y is bf16 (uint4 x4 per node); folds previous layer's BN finalize.

template <int AFF>
__global__ __launch_bounds__(256) void k_transform(const void* __restrict__ xin, const float* __restrict__ W,
                                                   const float* __restrict__ sSum, const float* __restrict__ sSq,
                                                   const float* __restrict__ bg, const float* __restrict__ bb,
                                                   uint4* __restrict__ pb, int n, float invN) {
    __shared__ float sW[32][32];
    __shared__ float sA[32], sC[32];
    int t = threadIdx.x;
    for (int i = t; i < 1024; i += 256) sW[i >> 5][i & 31] = W[i];
    if (AFF && t < 32) bn_coef(sSum, sSq, bg, bb, invN, t, &sA[t], &sC[t]);
    __syncthreads();
    int node = blockIdx.x * 256 + t;
    if (node >= n) return;
    float x[32];
    if (AFF) {
        const uint4* y4 = (const uint4*)xin + (size_t)node * 4;
#pragma unroll
        for (int q = 0; q < 4; q++) {
            uint4 u = y4[q];
            x[8*q+0] = bfLO(u.x); x[8*q+1] = bfHI(u.x);
            x[8*q+2] = bfLO(u.y); x[8*q+3] = bfHI(u.y);
            x[8*q+4] = bfLO(u.z); x[8*q+5] = bfHI(u.z);
            x[8*q+6] = bfLO(u.w); x[8*q+7] = bfHI(u.w);
        }
#pragma unroll
        for (int k = 0; k < 32; k++) {
            float v = sA[k] * x[k] + sC[k];
            x[k] = v > 0.f ? v : 0.f;
        }
    } else {
        const float4* s4 = (const float4*)xin + (size_t)node * 8;
#pragma unroll
        for (int q = 0; q < 8; q++) {
            float4 v = s4[q];
            x[4*q] = v.x; x[4*q+1] = v.y; x[4*q+2] = v.z; x[4*q+3] = v.w;
        }
    }
    float acc[32];
#pragma unroll
    for (int f = 0; f < 32; f++) acc[f] = 0.f;
#pragma unroll
    for (int k = 0; k < 32; k++) {
        float xv = x[k];
#pragma unroll
        for (int f = 0; f < 32; f++) acc[f] += xv * sW[k][f];
    }
    uint4* d4 = pb + (size_t)node * 4;
#pragma unroll
    for (int q = 0; q < 4; q++) {
        uint4 o;
        o.x = bf16pack2(acc[8*q+0], acc[8*q+1]);
        o.y = bf16pack2(acc[8*q+2], acc[8*q+3]);
        o.z = bf16pack2(acc[8*q+4], acc[8*q+5]);
        o.w = bf16pack2(acc[8*q+6], acc[8*q+7]);
        d4[q] = o;
    }
}

// layer 3: p3[v] = relu(a*y2+c) . w3   (bf16 y2 input, fp32 out; folds its BN coefs)
__global__ __launch_bounds__(256) void k_transform3(const uint4* __restrict__ y2, const float* __restrict__ w3,
                                                    const float* __restrict__ sSum, const float* __restrict__ sSq,
                                                    const float* __restrict__ bg, const float* __restrict__ bb,
                                                    float* __restrict__ p3, int n, float invN) {
    __shared__ float sw[32], sA[32], sC[32];
    int t = threadIdx.x;
    if (t < 32) { sw[t] = w3[t]; bn_coef(sSum, sSq, bg, bb, invN, t, &sA[t], &sC[t]); }
    __syncthreads();
    int i = blockIdx.x * 256 + t;
    if (i >= n) return;
    const uint4* x4 = y2 + (size_t)i * 4;
    float acc = 0.f;
#pragma unroll
    for (int q = 0; q < 4; q++) {
        uint4 u = x4[q];
        float vv[8] = { bfLO(u.x), bfHI(u.x), bfLO(u.y), bfHI(u.y),
                        bfLO(u.z), bfHI(u.z), bfLO(u.w), bfHI(u.w) };
#pragma unroll
        for (int r = 0; r < 8; r++) {
            int k = q * 8 + r;
            float xv = sA[k] * vv[r] + sC[k];
            xv = xv > 0.f ? xv : 0.f;
            acc += xv * sw[k];
        }
    }
    p3[i] = acc;
}

// ---------------- aggregation: y[v] = mean_{u->v} p[u] + bias; fused BN stats; bf16 y out -------
// bf16 p: 4 lanes/node, 16B (8 bf16 ch)/lane, one node per 4-lane group, 8-deep unroll.
// Block's 64 nodes own a contiguous col window -> stage to LDS.

__global__ __launch_bounds__(256) void k_aggregate(const uint4* __restrict__ pb, const int* __restrict__ rs,
                                                   const int* __restrict__ re, const int* __restrict__ col,
                                                   const float* __restrict__ bias,
                                                   uint4* __restrict__ yb, float* __restrict__ sSum,
                                                   float* __restrict__ sSq, int n) {
    __shared__ int scol[2048];
    int t = threadIdx.x;
    int lane = t & 3;          // 16B chunk: channels lane*8 .. lane*8+7
    int grp = t >> 2;          // 0..63 : node within block
    int node0 = blockIdx.x * 64;
    int node = node0 + grp;
    int base0 = 0, len = 0;
    if (node0 < n) {
        int last = node0 + 63; if (last > n - 1) last = n - 1;
        base0 = rs[node0];
        len = re[last] - base0;
    }
    bool lds = (len > 0 && len <= 2048);    // block-uniform; mean 1024
    if (lds) { for (int i = t; i < len; i += 256) scol[i] = col[base0 + i]; }
    __syncthreads();

    float accA[8], accB[8];
#pragma unroll
    for (int q = 0; q < 8; q++) { accA[q] = 0.f; accB[q] = 0.f; }
    float vout[8];
#pragma unroll
    for (int q = 0; q < 8; q++) vout[q] = 0.f;
    if (node < n) {
        int s0 = rs[node], s1 = re[node];
#define GATH(vv, c) uint4 vv = pb[(size_t)(c) * 4 + lane]
#define ACC(dst, vv) \
        dst[0] += bfLO((vv).x); dst[1] += bfHI((vv).x); \
        dst[2] += bfLO((vv).y); dst[3] += bfHI((vv).y); \
        dst[4] += bfLO((vv).z); dst[5] += bfHI((vv).z); \
        dst[6] += bfLO((vv).w); dst[7] += bfHI((vv).w)
        if (lds) {
            int j = s0 - base0, j1 = s1 - base0;
            for (; j + 8 <= j1; j += 8) {
                int c0 = scol[j], c1 = scol[j + 1], c2 = scol[j + 2], c3 = scol[j + 3];
                int c4 = scol[j + 4], c5 = scol[j + 5], c6 = scol[j + 6], c7 = scol[j + 7];
                GATH(g0, c0); GATH(g1, c1); GATH(g2, c2); GATH(g3, c3);
                GATH(g4, c4); GATH(g5, c5); GATH(g6, c6); GATH(g7, c7);
                ACC(accA, g0); ACC(accB, g1); ACC(accA, g2); ACC(accB, g3);
                ACC(accA, g4); ACC(accB, g5); ACC(accA, g6); ACC(accB, g7);
            }
            for (; j < j1; ++j) { GATH(g, scol[j]); ACC(accA, g); }
        } else {
            for (int j = s0; j < s1; ++j) { GATH(g, col[j]); ACC(accA, g); }
        }
#undef GATH
#undef ACC
        int deg = s1 - s0;
        float inv = (deg > 0) ? 1.f / (float)deg : 1.f;
        const float4* b4 = (const float4*)bias;
        float4 b0 = b4[lane * 2], b1 = b4[lane * 2 + 1];
        vout[0] = (accA[0] + accB[0]) * inv + b0.x;
        vout[1] = (accA[1] + accB[1]) * inv + b0.y;
        vout[2] = (accA[2] + accB[2]) * inv + b0.z;
        vout[3] = (accA[3] + accB[3]) * inv + b0.w;
        vout[4] = (accA[4] + accB[4]) * inv + b1.x;
        vout[5] = (accA[5] + accB[5]) * inv + b1.y;
        vout[6] = (accA[6] + accB[6]) * inv + b1.z;
        vout[7] = (accA[7] + accB[7]) * inv + b1.w;
        uint4 o;
        o.x = bf16pack2(vout[0], vout[1]);
        o.y = bf16pack2(vout[2], vout[3]);
        o.z = bf16pack2(vout[4], vout[5]);
        o.w = bf16pack2(vout[6], vout[7]);
        yb[(size_t)node * 4 + lane] = o;
    }
    // BN stats (fp32, pre-rounding): channel = lane*8 + q
    __shared__ float sS[64][32];
    __shared__ float sQ[64][32];
    ((float4*)&sS[grp][lane * 8])[0] = make_float4(vout[0], vout[1], vout[2], vout[3]);
    ((float4*)&sS[grp][lane * 8])[1] = make_float4(vout[4], vout[5], vout[6], vout[7]);
    ((float4*)&sQ[grp][lane * 8])[0] = make_float4(vout[0]*vout[0], vout[1]*vout[1], vout[2]*vout[2], vout[3]*vout[3]);
    ((float4*)&sQ[grp][lane * 8])[1] = make_float4(vout[4]*vout[4], vout[5]*vout[5], vout[6]*vout[6], vout[7]*vout[7]);
    __syncthreads();
    if (t < 32) {
        float S = 0.f, Q = 0.f;
#pragma unroll
        for (int g2 = 0; g2 < 64; g2++) { S += sS[g2][t]; Q += sQ[g2][t]; }
        int slot = blockIdx.x & (NSLOT - 1);
        atomicAdd(&sSum[slot * 32 + t], S);
        atomicAdd(&sSq[slot * 32 + t], Q);
    }
}

__global__ __launch_bounds__(256) void k_aggregate3(const float* __restrict__ p3, const int* __restrict__ rs,
                                                    const int* __restrict__ re, const int* __restrict__ col,
                                                    const float* __restrict__ b1,
                                                    float* __restrict__ y3, float* __restrict__ sSum,
                                                    float* __restrict__ sSq, int n) {
    int i = blockIdx.x * 256 + threadIdx.x;
    float lsum = 0.f, lsq = 0.f;
    if (i < n) {
        int s0 = rs[i], s1 = re[i];
        float a0 = 0.f, a1 = 0.f, a2 = 0.f, a3 = 0.f;
        int j = s0;
        for (; j + 4 <= s1; j += 4) {
            int c0 = col[j], c1 = col[j + 1], c2 = col[j + 2], c3 = col[j + 3];
            a0 += p3[c0]; a1 += p3[c1]; a2 += p3[c2]; a3 += p3[c3];
        }
        for (; j < s1; ++j) a0 += p3[col[j]];
        float acc = (a0 + a1) + (a2 + a3);
        float inv = (s1 > s0) ? 1.f / (float)(s1 - s0) : 1.f;
        float v = acc * inv + b1[0];
        y3[i] = v; lsum = v; lsq = v * v;
    }
    __shared__ float sS[256], sQ[256];
    int t = threadIdx.x;
    sS[t] = lsum; sQ[t] = lsq;
    __syncthreads();
    for (int s = 128; s > 0; s >>= 1) {
        if (t < s) { sS[t] += sS[t + s]; sQ[t] += sQ[t + s]; }
        __syncthreads();
    }
    if (t == 0) {
        int slot = blockIdx.x & (NSLOT - 1);
        atomicAdd(&sSum[slot * 32], sS[0]);
        atomicAdd(&sSq[slot * 32], sQ[0]);
    }
}

// ---------------- per-graph mean pool + MLP (folds all 97 BN coefs; bf16 y inputs) --------------

__global__ __launch_bounds__(256) void k_pool_mlp(const float* __restrict__ h,
                                                  const unsigned* __restrict__ y0b,
                                                  const unsigned* __restrict__ y1b,
                                                  const unsigned* __restrict__ y2b,
                                                  const float* __restrict__ y3,
                                                  const float* __restrict__ sSum, const float* __restrict__ sSq,
                                                  const float* __restrict__ bg0, const float* __restrict__ bb0,
                                                  const float* __restrict__ bg1, const float* __restrict__ bb1,
                                                  const float* __restrict__ bg2, const float* __restrict__ bb2,
                                                  const float* __restrict__ bg3, const float* __restrict__ bb3,
                                                  const int* __restrict__ gstart,
                                                  const float* __restrict__ w0, const float* __restrict__ b0,
                                                  const float* __restrict__ w1, const float* __restrict__ b1,
                                                  const float* __restrict__ w2, const float* __restrict__ b2,
                                                  float* __restrict__ out, float invN) {
    __shared__ float pcA[128], pcC[128];
    int g = blockIdx.x;
    int t = threadIdx.x;
    if (t < 97) {
        int layer = (t == 96) ? 3 : (t >> 5);
        int ch = t & 31;
        const float* bg = (layer == 0) ? bg0 : (layer == 1) ? bg1 : (layer == 2) ? bg2 : bg3;
        const float* bb = (layer == 0) ? bb0 : (layer == 1) ? bb1 : (layer == 2) ? bb2 : bb3;
        bn_coef(sSum + layer * NSLOT * 32, sSq + layer * NSLOT * 32, bg, bb, invN, ch, &pcA[t], &pcC[t]);
    }
    __syncthreads();
    int s0 = gstart[g], s1 = gstart[g + 1];
    int lane = t & 31, slot = t >> 5;
    int arr = lane >> 3, sub = lane & 7;
    const unsigned* yb = (arr == 1) ? y0b : (arr == 2) ? y1b : y2b;
    float4 a4 = make_float4(1.f, 1.f, 1.f, 1.f);
    float4 c4 = make_float4(0.f, 0.f, 0.f, 0.f);
    bool aff = (arr > 0);
    if (aff) {
        a4 = ((const float4*)pcA)[(arr - 1) * 8 + sub];
        c4 = ((const float4*)pcC)[(arr - 1) * 8 + sub];
    }
    float4 acc = make_float4(0.f, 0.f, 0.f, 0.f);
    for (int n = s0 + slot; n < s1; n += 8) {
        float4 v;
        if (arr == 0) {
            v = ((const float4*)h)[(size_t)n * 8 + sub];
        } else {
            uint2 u = ((const uint2*)yb)[(size_t)n * 8 + sub];   // 4 bf16 ch
            v = make_float4(bfLO(u.x), bfHI(u.x), bfLO(u.y), bfHI(u.y));
        }
        if (aff) {
            float vx = fmaf(a4.x, v.x, c4.x); vx = vx > 0.f ? vx : 0.f;
            float vy = fmaf(a4.y, v.y, c4.y); vy = vy > 0.f ? vy : 0.f;
            float vz = fmaf(a4.z, v.z, c4.z); vz = vz > 0.f ? vz : 0.f;
            float vw = fmaf(a4.w, v.w, c4.w); vw = vw > 0.f ? vw : 0.f;
            v = make_float4(vx, vy, vz, vw);
        }
        acc = f4add(acc, v);
    }
    __shared__ float sP[8][128];
    __shared__ float sY[8];
    ((float4*)&sP[slot][lane * 4])[0] = acc;
    if (t < 8) {
        float a = pcA[96], c = pcC[96], s = 0.f;
        for (int n = s0 + t; n < s1; n += 8) {
            float v = fmaf(a, y3[n], c);
            s += v > 0.f ? v : 0.f;
        }
        sY[t] = s;
    }
    __syncthreads();
    __shared__ float hg[129];
    __shared__ float hid1[128];
    __shared__ float hid2[64];
    float inv = (s1 > s0) ? 1.f / (float)(s1 - s0) : 1.f;
    if (t < 128) {
        float S = 0.f;
#pragma unroll
        for (int s = 0; s < 8; s++) S += sP[s][t];
        hg[t] = S * inv;
    } else if (t == 128) {
        float S = 0.f;
#pragma unroll
        for (int s = 0; s < 8; s++) S += sY[s];
        hg[128] = S * inv;
    }
    __syncthreads();
    if (t < 128) {
        float a = b0[t];
        for (int i = 0; i < 129; i++) a += hg[i] * w0[i * 128 + t];
        hid1[t] = a > 0.f ? a : 0.f;
    }
    __syncthreads();
    if (t < 64) {
        float a = b1[t];
        for (int i = 0; i < 128; i++) a += hid1[i] * w1[i * 64 + t];
        hid2[t] = a > 0.f ? a : 0.f;
    }
    __syncthreads();
    if (t < 64) {
        float v = hid2[t] * w2[t];
        for (int off = 32; off > 0; off >>= 1) v += __shfl_down(v, off, 64);
        if (t == 0) out[g] = v + b2[0];
    }
}

// ---------------- launcher ----------------

extern "C" void kernel_launch(void* const* d_in, const int* in_sizes, int n_in,
                              void* d_out, int out_size, void* d_ws, size_t ws_size,
                              hipStream_t stream) {
    const float* h   = (const float*)d_in[0];
    const int* src   = (const int*)d_in[1];
    const int* dst   = (const int*)d_in[2];
    const int* gid   = (const int*)d_in[3];
    const float* convw[4], *convb[4], *bng[4], *bnb[4];
    for (int i = 0; i < 4; i++) {
        convw[i] = (const float*)d_in[4 + 4 * i];
        convb[i] = (const float*)d_in[5 + 4 * i];
        bng[i]   = (const float*)d_in[6 + 4 * i];
        bnb[i]   = (const float*)d_in[7 + 4 * i];
    }
    const float* mw0 = (const float*)d_in[20];
    const float* mb0 = (const float*)d_in[21];
    const float* mw1 = (const float*)d_in[22];
    const float* mb1 = (const float*)d_in[23];
    const float* mw2 = (const float*)d_in[24];
    const float* mb2 = (const float*)d_in[25];

    const int N = in_sizes[0] / 32;
    const int E = in_sizes[1];
    const int G = out_size;
    const int nbuck = cdiv_h(N, BKN);          // <= MAXBUCK for N <= 131072
    const int chunk = cdiv_h(E, NSB);

    // workspace bump allocator (512B aligned)
    char* ws = (char*)d_ws;
    size_t off = 0;
    auto alloc = [&](size_t bytes) -> void* {
        void* p = ws + off;
        off += (bytes + 511) & ~(size_t)511;
        return p;
    };
    int* histT   = (int*)alloc((size_t)NSB * nbuck * 4);
    int* prefixB = (int*)alloc((size_t)nbuck * NSB * 4);
    int* totalP  = (int*)alloc((size_t)nbuck * 4);
    int* totalU  = (int*)alloc((size_t)nbuck * 4);
    int* basePp  = (int*)alloc((size_t)nbuck * 4);
    int* baseUp  = (int*)alloc((size_t)nbuck * 4);
    size_t ebufE = (size_t)E + (size_t)16 * NSB * nbuck;      // padded capacity (ints)
    size_t ovl   = ebufE * 4;
    size_t pB    = (size_t)N * 64;                            // p bf16: 64 B/node
    if (pB > ovl) ovl = pB;
    unsigned* ebuf = (unsigned*)alloc(ovl);                    // overlay: ebuf dead after k_sortb
    uint4* pb    = (uint4*)ebuf;
    int* col     = (int*)alloc((size_t)E * 4);
    int* rs      = (int*)alloc((size_t)N * 4);
    int* re      = (int*)alloc((size_t)N * 4);
    int* gstart  = (int*)alloc((size_t)(G + 1) * 4);
    uint4* y0b   = (uint4*)alloc((size_t)N * 64);              // bf16 y: 64 B/node
    uint4* y1b   = (uint4*)alloc((size_t)N * 64);
    uint4* y2b   = (uint4*)alloc((size_t)N * 64);
    float* y3    = (float*)alloc((size_t)N * 4);
    float* sSum  = (float*)alloc((size_t)4 * NSLOT * 32 * 4);
    float* sSq   = (float*)alloc((size_t)4 * NSLOT * 32 * 4);
    (void)ws_size; (void)n_in;

    const int NB_N = cdiv_h(N, 256);
    const int NB_AG = cdiv_h(N, 64);   // one node per 4-lane group
    const float invN = 1.f / (float)N;

    // edge grouping: two-pass deterministic scatter (zero global atomics) + per-bucket sort
    k_hist<<<NSB, 256, 0, stream>>>(dst, histT, sSum, sSq, E, nbuck, chunk);
    k_scanA<<<nbuck, 256, 0, stream>>>(histT, prefixB, totalP, totalU, gid, gstart, nbuck, N, G);
    k_scanB<<<1, 512, 0, stream>>>(totalP, totalU, basePp, baseUp, nbuck);
    k_scatter2<<<NSB, 256, 0, stream>>>(src, dst, basePp, prefixB, ebuf, E, nbuck, chunk);
    k_sortb<<<nbuck, 256, 0, stream>>>(ebuf, histT, basePp, prefixB, baseUp, col, rs, re, nbuck, N);

    // layer 0
    k_transform<0><<<NB_N, 256, 0, stream>>>(h, convw[0], nullptr, nullptr, nullptr, nullptr, pb, N, invN);
    k_aggregate<<<NB_AG, 256, 0, stream>>>(pb, rs, re, col, convb[0], y0b,
                                           sSum + 0 * NSLOT * 32, sSq + 0 * NSLOT * 32, N);
    // layer 1 (folds layer-0 BN finalize)
    k_transform<1><<<NB_N, 256, 0, stream>>>(y0b, convw[1], sSum + 0 * NSLOT * 32, sSq + 0 * NSLOT * 32,
                                             bng[0], bnb[0], pb, N, invN);
    k_aggregate<<<NB_AG, 256, 0, stream>>>(pb, rs, re, col, convb[1], y1b,
                                           sSum + 1 * NSLOT * 32, sSq + 1 * NSLOT * 32, N);
    // layer 2 (folds layer-1 BN finalize)
    k_transform<1><<<NB_N, 256, 0, stream>>>(y1b, convw[2], sSum + 1 * NSLOT * 32, sSq + 1 * NSLOT * 32,
                                             bng[1], bnb[1], pb, N, invN);
    k_aggregate<<<NB_AG, 256, 0, stream>>>(pb, rs, re, col, convb[2], y2b,
                                           sSum + 2 * NSLOT * 32, sSq + 2 * NSLOT * 32, N);
    // layer 3 (32 -> 1, pre-multiplied; folds layer-2 BN finalize)
    k_transform3<<<NB_N, 256, 0, stream>>>(y2b, convw[3], sSum + 2 * NSLOT * 32, sSq + 2 * NSLOT * 32,
                                           bng[2], bnb[2], (float*)pb, N, invN);
    k_aggregate3<<<NB_N, 256, 0, stream>>>((float*)pb, rs, re, col, convb[3], y3,
                                           sSum + 3 * NSLOT * 32, sSq + 3 * NSLOT * 32, N);

    // pooling + MLP (folds all BN coefs)
    k_pool_mlp<<<G, 256, 0, stream>>>(h, (const unsigned*)y0b, (const unsigned*)y1b, (const unsigned*)y2b,
                                      y3, sSum, sSq,
                                      bng[0], bnb[0], bng[1], bnb[1], bng[2], bnb[2], bng[3], bnb[3],
                                      gstart, mw0, mb0, mw1, mb1, mw2, mb2, (float*)d_out, invN);
}